// Round 9
// baseline (2181.338 us; speedup 1.0000x reference)
//
#include <hip/hip_runtime.h>

// Problem constants
#define NB 16
#define NH 64
#define NW 64
#define ND 128
#define NK 4096
#define NROWS (NB * NH * NW)        // 65536
#define NSLICE 4
#define SLICE_K (NK / NSLICE)       // 1024
#define OUT_ELEMS (NB * ND * NH * NW)  // 8388608
#define MARGIN_F 0.05f

typedef short bf16x8 __attribute__((ext_vector_type(8)));
typedef float f32x4 __attribute__((ext_vector_type(4)));

__device__ __forceinline__ unsigned short f2bf_rne(float x) {
    unsigned int u = __float_as_uint(x);
    u += 0x7FFFu + ((u >> 16) & 1u);
    return (unsigned short)(u >> 16);
}
__device__ __forceinline__ float bf2f(unsigned short h) {
    return __uint_as_float(((unsigned int)h) << 16);
}

// ---------------------------------------------------------------------------
// Kernel 1: emb prep — enorm[k] = ||emb[k]||^2 (fp32 exact) + split-bf16
// e_hi/e_lo. One wave per code.
// ---------------------------------------------------------------------------
__global__ void emb_prep_kernel(const float* __restrict__ emb,
                                float* __restrict__ enorm,
                                unsigned short* __restrict__ e_hi,
                                unsigned short* __restrict__ e_lo) {
    int wave = (blockIdx.x * blockDim.x + threadIdx.x) >> 6;
    int lane = threadIdx.x & 63;
    if (wave >= NK) return;
    const float* e = emb + (size_t)wave * ND;
    float a = e[lane];
    float b = e[lane + 64];
    unsigned short ah = f2bf_rne(a), bh = f2bf_rne(b);
    e_hi[(size_t)wave * ND + lane] = ah;
    e_hi[(size_t)wave * ND + lane + 64] = bh;
    e_lo[(size_t)wave * ND + lane] = f2bf_rne(a - bf2f(ah));
    e_lo[(size_t)wave * ND + lane + 64] = f2bf_rne(b - bf2f(bh));
    float s = a * a + b * b;
#pragma unroll
    for (int off = 32; off > 0; off >>= 1) s += __shfl_down(s, off, 64);
    if (lane == 0) enorm[wave] = s;
}

// ---------------------------------------------------------------------------
// Kernel 2: MFMA argmin.
// R8: VGPR=128 + 217MB spill writes — launch_bounds(256,2) only sets MIN
// waves/EU; compiler shrank regs for occupancy and spilled. Fix:
// amdgpu_waves_per_eu(2,2) pins occupancy target (budget 256 regs), and the
// kk-loop is ni-major (B frags 8 regs live, not 32). Peak live ~170 regs.
// dot = hi*hi + hi*lo + lo*hi; rows with best2-best1 < MARGIN_F rescued.
// ---------------------------------------------------------------------------
#define ZST 136   // LDS row stride in ushort

__global__ void
__attribute__((amdgpu_flat_work_group_size(256, 256), amdgpu_waves_per_eu(2, 2)))
mfma_argmin_kernel(const float* __restrict__ z,
                   const unsigned short* __restrict__ e_hi,
                   const unsigned short* __restrict__ e_lo,
                   const float* __restrict__ enorm,
                   int* __restrict__ idx_out,
                   int* __restrict__ rcount,
                   int* __restrict__ rlist) {
    __shared__ unsigned short zh[64 * ZST];
    __shared__ unsigned short zl[64 * ZST];
    __shared__ float redb1[NSLICE * 64];
    __shared__ float redb2[NSLICE * 64];
    __shared__ int redi1[NSLICE * 64];

    const int bid = blockIdx.x;
    const int rowbase = bid * 64;
    const int t = threadIdx.x;

    const float4* zg = (const float4*)(z + (size_t)rowbase * ND);
#pragma unroll
    for (int q = 0; q < 8; q++) {
        int i = t + 256 * q;               // 0..2047
        float4 v = zg[i];
        int r = i >> 5;
        int c4 = (i & 31) << 2;
        unsigned short h0 = f2bf_rne(v.x), h1 = f2bf_rne(v.y),
                       h2 = f2bf_rne(v.z), h3 = f2bf_rne(v.w);
        ushort4 hv = make_ushort4(h0, h1, h2, h3);
        ushort4 lv = make_ushort4(f2bf_rne(v.x - bf2f(h0)),
                                  f2bf_rne(v.y - bf2f(h1)),
                                  f2bf_rne(v.z - bf2f(h2)),
                                  f2bf_rne(v.w - bf2f(h3)));
        *(ushort4*)&zh[r * ZST + c4] = hv;
        *(ushort4*)&zl[r * ZST + c4] = lv;
    }
    __syncthreads();

    const int lane = t & 63;
    const int wid = __builtin_amdgcn_readfirstlane(t >> 6);
    const int quad = lane >> 4;
    const int c = lane & 15;
    const int n0 = wid * SLICE_K;

    float b1[4][4], b2[4][4];
    int i1[4][4];
#pragma unroll
    for (int mi = 0; mi < 4; mi++)
#pragma unroll
        for (int r = 0; r < 4; r++) { b1[mi][r] = 3.4e38f; b2[mi][r] = 3.4e38f; i1[mi][r] = 0; }

    const int aoff = c * ZST + quad * 8;
    const unsigned short* pbh = e_hi + c * ND + quad * 8;
    const unsigned short* pbl = e_lo + c * ND + quad * 8;

    for (int nb = n0; nb < n0 + SLICE_K; nb += 64) {
        f32x4 acc[4][4];
#pragma unroll
        for (int mi = 0; mi < 4; mi++)
#pragma unroll
            for (int ni = 0; ni < 4; ni++) acc[mi][ni] = (f32x4){0.f, 0.f, 0.f, 0.f};

#pragma unroll
        for (int kk = 0; kk < 4; kk++) {
            bf16x8 ah[4], al[4];
#pragma unroll
            for (int mi = 0; mi < 4; mi++) {
                ah[mi] = *(const bf16x8*)&zh[aoff + mi * (16 * ZST) + kk * 32];
                al[mi] = *(const bf16x8*)&zl[aoff + mi * (16 * ZST) + kk * 32];
            }
            // ni-major: only one (bh,bl) pair live at a time (8 regs, not 32)
#pragma unroll
            for (int ni = 0; ni < 4; ni++) {
                size_t boff = (size_t)(nb + ni * 16) * ND + kk * 32;
                bf16x8 bhv = *(const bf16x8*)(pbh + boff);
                bf16x8 blv = *(const bf16x8*)(pbl + boff);
#pragma unroll
                for (int mi = 0; mi < 4; mi++) {
                    acc[mi][ni] = __builtin_amdgcn_mfma_f32_16x16x32_bf16(ah[mi], bhv, acc[mi][ni], 0, 0, 0);
                    acc[mi][ni] = __builtin_amdgcn_mfma_f32_16x16x32_bf16(ah[mi], blv, acc[mi][ni], 0, 0, 0);
                    acc[mi][ni] = __builtin_amdgcn_mfma_f32_16x16x32_bf16(al[mi], bhv, acc[mi][ni], 0, 0, 0);
                }
            }
        }

#pragma unroll
        for (int ni = 0; ni < 4; ni++) {
            int n = nb + ni * 16 + c;
            float en = enorm[n];
#pragma unroll
            for (int mi = 0; mi < 4; mi++)
#pragma unroll
                for (int r = 0; r < 4; r++) {
                    float s = fmaf(-2.0f, acc[mi][ni][r], en);
                    if (s < b1[mi][r]) { b2[mi][r] = b1[mi][r]; b1[mi][r] = s; i1[mi][r] = n; }
                    else if (s < b2[mi][r]) b2[mi][r] = s;
                }
        }
    }

#pragma unroll
    for (int off = 1; off < 16; off <<= 1) {
#pragma unroll
        for (int mi = 0; mi < 4; mi++)
#pragma unroll
            for (int r = 0; r < 4; r++) {
                float ob1 = __shfl_xor(b1[mi][r], off, 64);
                float ob2 = __shfl_xor(b2[mi][r], off, 64);
                int oi1 = __shfl_xor(i1[mi][r], off, 64);
                float lo = fminf(b1[mi][r], ob1);
                float hi = fmaxf(b1[mi][r], ob1);
                b2[mi][r] = fminf(fminf(b2[mi][r], ob2), hi);
                i1[mi][r] = (ob1 < b1[mi][r]) ? oi1 : i1[mi][r];
                b1[mi][r] = lo;
            }
    }

    if (c == 0) {
#pragma unroll
        for (int mi = 0; mi < 4; mi++)
#pragma unroll
            for (int r = 0; r < 4; r++) {
                int row = mi * 16 + quad * 4 + r;
                redb1[wid * 64 + row] = b1[mi][r];
                redb2[wid * 64 + row] = b2[mi][r];
                redi1[wid * 64 + row] = i1[mi][r];
            }
    }
    __syncthreads();

    if (t < 64) {
        float B1 = redb1[t], B2 = redb2[t];
        int I1 = redi1[t];
#pragma unroll
        for (int sl = 1; sl < NSLICE; sl++) {
            float ob1 = redb1[sl * 64 + t];
            float ob2 = redb2[sl * 64 + t];
            int oi1 = redi1[sl * 64 + t];
            float lo = fminf(B1, ob1);
            float hi = fmaxf(B1, ob1);
            B2 = fminf(fminf(B2, ob2), hi);
            I1 = (ob1 < B1) ? oi1 : I1;
            B1 = lo;
        }
        idx_out[rowbase + t] = I1;
        if (B2 - B1 < MARGIN_F) {
            int p = atomicAdd(rcount, 1);
            rlist[p] = rowbase + t;
        }
    }
}

// ---------------------------------------------------------------------------
// Kernel 3: exact fp32 rescue, 8 rows per block (R8 shape streamed 2MB of
// emb PER ROW; now amortized 8x). Named scalar accs/trackers (R4/R6 lesson).
// Per-thread k = j*256 + t ascending + strict < => first-index; merges carry
// smaller-index tie-break.
// ---------------------------------------------------------------------------
#define RR 8

#define ROWFMA(R) { float4 zv = zs4[R * 32 + d]; \
    a##R = fmaf(zv.x, ev.x, a##R); a##R = fmaf(zv.y, ev.y, a##R); \
    a##R = fmaf(zv.z, ev.z, a##R); a##R = fmaf(zv.w, ev.w, a##R); }

#define ROWSEL(R) { float s = fmaf(-2.0f, a##R, en); \
    if (s < b##R) { b##R = s; i##R = k; } }

#define REDROW(R) { float bb = b##R; int ii = i##R; \
    _Pragma("unroll") \
    for (int off = 32; off > 0; off >>= 1) { \
        float ob = __shfl_down(bb, off, 64); \
        int oi = __shfl_down(ii, off, 64); \
        if (ob < bb || (ob == bb && oi < ii)) { bb = ob; ii = oi; } \
    } \
    if (lane == 0) { rbw[wv][R] = bb; riw[wv][R] = ii; } }

__global__ void __launch_bounds__(256, 4)
rescue_kernel(const float* __restrict__ z,
              const float* __restrict__ emb,
              const float* __restrict__ enorm,
              const int* __restrict__ rcount,
              const int* __restrict__ rlist,
              int* __restrict__ idx_out) {
    __shared__ float4 zs4[RR * 32];
    __shared__ int ids[RR];
    __shared__ float rbw[4][RR];
    __shared__ int riw[4][RR];

    const int t = threadIdx.x;
    const int lane = t & 63;
    const int wv = t >> 6;
    const int cnt = *rcount;
    if (cnt == 0) return;
    const int ngrp = (cnt + RR - 1) / RR;

    for (int g = blockIdx.x; g < ngrp; g += gridDim.x) {
        const int base = g * RR;
        if (t < RR) {
            int j = base + t;
            ids[t] = rlist[j < cnt ? j : cnt - 1];
        }
        __syncthreads();
        if (t < RR * 32) {
            int r = t >> 5, d = t & 31;
            zs4[t] = ((const float4*)(z + (size_t)ids[r] * ND))[d];
        }
        __syncthreads();

        float b0 = 3.4e38f, b1 = 3.4e38f, b2 = 3.4e38f, b3 = 3.4e38f,
              b4 = 3.4e38f, b5 = 3.4e38f, b6 = 3.4e38f, b7 = 3.4e38f;
        int i0 = 0, i1 = 0, i2 = 0, i3 = 0, i4 = 0, i5 = 0, i6 = 0, i7 = 0;

        for (int j = 0; j < 16; j++) {
            int k = j * 256 + t;                       // ascending per thread
            const float4* e4 = (const float4*)(emb + (size_t)k * ND);
            float a0 = 0.f, a1 = 0.f, a2 = 0.f, a3 = 0.f,
                  a4 = 0.f, a5 = 0.f, a6 = 0.f, a7 = 0.f;
#pragma unroll
            for (int d = 0; d < 32; d++) {
                float4 ev = e4[d];
                ROWFMA(0) ROWFMA(1) ROWFMA(2) ROWFMA(3)
                ROWFMA(4) ROWFMA(5) ROWFMA(6) ROWFMA(7)
            }
            float en = enorm[k];
            ROWSEL(0) ROWSEL(1) ROWSEL(2) ROWSEL(3)
            ROWSEL(4) ROWSEL(5) ROWSEL(6) ROWSEL(7)
        }

        REDROW(0) REDROW(1) REDROW(2) REDROW(3)
        REDROW(4) REDROW(5) REDROW(6) REDROW(7)
        __syncthreads();

        if (t < RR && base + t < cnt) {
            float B = rbw[0][t]; int I = riw[0][t];
#pragma unroll
            for (int w2 = 1; w2 < 4; w2++) {
                if (rbw[w2][t] < B || (rbw[w2][t] == B && riw[w2][t] < I)) {
                    B = rbw[w2][t]; I = riw[w2][t];
                }
            }
            idx_out[ids[t]] = I;
        }
        __syncthreads();   // protect LDS before next group
    }
}

// ---------------------------------------------------------------------------
// Kernel 4: gather + loss partial + transposed write (unchanged).
// ---------------------------------------------------------------------------
__global__ void out_kernel(const float* __restrict__ z,
                           const float* __restrict__ emb,
                           const int* __restrict__ idx,
                           float* __restrict__ out,
                           float* __restrict__ losspart) {
    __shared__ float zq[64 * 129];
    __shared__ int ids[64];
    __shared__ float redl[4];

    const int bid = blockIdx.x;
    const int b = bid >> 6;
    const int h = bid & 63;
    const int rowbase = bid * 64;
    const int t = threadIdx.x;

    if (t < 64) ids[t] = idx[rowbase + t];
    __syncthreads();

    const int d = t & 127;
    const int w0 = t >> 7;
    float lsum = 0.f;
#pragma unroll
    for (int wq = 0; wq < 32; wq++) {
        int w = w0 + 2 * wq;
        float e = emb[(size_t)ids[w] * ND + d];
        float zv = z[((size_t)(rowbase + w)) * ND + d];
        float df = e - zv;
        lsum = fmaf(df, df, lsum);
        zq[w * 129 + d] = e;
    }
#pragma unroll
    for (int off = 32; off > 0; off >>= 1) lsum += __shfl_down(lsum, off, 64);
    if ((t & 63) == 0) redl[t >> 6] = lsum;
    __syncthreads();
    if (t == 0) losspart[bid] = redl[0] + redl[1] + redl[2] + redl[3];

    const int w = t & 63;
    const int dq = t >> 6;
#pragma unroll
    for (int dd0 = 0; dd0 < 32; dd0++) {
        int dd = dq + 4 * dd0;
        out[(((size_t)b * ND + dd) * NH + h) * NW + w] = zq[w * 129 + dd];
    }
}

// ---------------------------------------------------------------------------
// Kernel 5: final loss reduce
// ---------------------------------------------------------------------------
__global__ void loss_kernel(const float* __restrict__ losspart,
                            float* __restrict__ out) {
    __shared__ float redl[4];
    const int t = threadIdx.x;
    float s = 0.f;
#pragma unroll
    for (int i = 0; i < 4; i++) s += losspart[t + 256 * i];
#pragma unroll
    for (int off = 32; off > 0; off >>= 1) s += __shfl_down(s, off, 64);
    if ((t & 63) == 0) redl[t >> 6] = s;
    __syncthreads();
    if (t == 0) {
        float total = redl[0] + redl[1] + redl[2] + redl[3];
        out[OUT_ELEMS] = 1.25f * total / (float)OUT_ELEMS;
    }
}

// ---------------------------------------------------------------------------
extern "C" void kernel_launch(void* const* d_in, const int* in_sizes, int n_in,
                              void* d_out, int out_size, void* d_ws, size_t ws_size,
                              hipStream_t stream) {
    const float* z = (const float*)d_in[0];      // [16,64,64,128] fp32
    const float* emb = (const float*)d_in[1];    // [4096,128] fp32
    float* out = (float*)d_out;                  // 8388608 + 1 fp32

    char* ws = (char*)d_ws;
    int* ws_idx = (int*)ws;                                   // 256 KB
    float* ws_enorm = (float*)(ws + (256 << 10));             // 16 KB
    float* ws_losspart = (float*)(ws + (272 << 10));          // 4 KB
    int* ws_rcount = (int*)(ws + (276 << 10));                // 256 B
    int* ws_rlist = (int*)(ws + (277 << 10));                 // 256 KB
    unsigned short* ws_ehi = (unsigned short*)(ws + (533 << 10));   // 1 MB
    unsigned short* ws_elo = (unsigned short*)(ws + (1557 << 10));  // 1 MB

    hipMemsetAsync(ws_rcount, 0, sizeof(int), stream);
    emb_prep_kernel<<<NK / 4, 256, 0, stream>>>(emb, ws_enorm, ws_ehi, ws_elo);
    mfma_argmin_kernel<<<NROWS / 64, 256, 0, stream>>>(z, ws_ehi, ws_elo,
                                                       ws_enorm, ws_idx,
                                                       ws_rcount, ws_rlist);
    rescue_kernel<<<512, 256, 0, stream>>>(z, emb, ws_enorm, ws_rcount,
                                           ws_rlist, ws_idx);
    out_kernel<<<NB * NH, 256, 0, stream>>>(z, emb, ws_idx, out, ws_losspart);
    loss_kernel<<<1, 256, 0, stream>>>(ws_losspart, out);
}

// Round 10
// 502.325 us; speedup vs baseline: 4.3425x; 4.3425x over previous
//
#include <hip/hip_runtime.h>

// Problem constants
#define NB 16
#define NH 64
#define NW 64
#define ND 128
#define NK 4096
#define NROWS (NB * NH * NW)        // 65536
#define NSLICE 4
#define SLICE_K (NK / NSLICE)       // 1024
#define OUT_ELEMS (NB * ND * NH * NW)  // 8388608
#define MARGIN_F 0.02f

typedef short bf16x8 __attribute__((ext_vector_type(8)));
typedef float f32x4 __attribute__((ext_vector_type(4)));

__device__ __forceinline__ unsigned short f2bf_rne(float x) {
    unsigned int u = __float_as_uint(x);
    u += 0x7FFFu + ((u >> 16) & 1u);
    return (unsigned short)(u >> 16);
}
__device__ __forceinline__ float bf2f(unsigned short h) {
    return __uint_as_float(((unsigned int)h) << 16);
}
// Order-preserving (score,idx) packing: smaller score first, then smaller idx.
__device__ __forceinline__ unsigned long long pack_si(float s, int idx) {
    unsigned int u = __float_as_uint(s);
    unsigned int key = ((int)u < 0) ? ~u : (u | 0x80000000u);
    return ((unsigned long long)key << 32) | (unsigned int)idx;
}

// ---------------------------------------------------------------------------
// Kernel 1: emb prep — enorm (fp32 exact) + split-bf16 e_hi/e_lo.
// ---------------------------------------------------------------------------
__global__ void emb_prep_kernel(const float* __restrict__ emb,
                                float* __restrict__ enorm,
                                unsigned short* __restrict__ e_hi,
                                unsigned short* __restrict__ e_lo) {
    int wave = (blockIdx.x * blockDim.x + threadIdx.x) >> 6;
    int lane = threadIdx.x & 63;
    if (wave >= NK) return;
    const float* e = emb + (size_t)wave * ND;
    float a = e[lane];
    float b = e[lane + 64];
    unsigned short ah = f2bf_rne(a), bh = f2bf_rne(b);
    e_hi[(size_t)wave * ND + lane] = ah;
    e_hi[(size_t)wave * ND + lane + 64] = bh;
    e_lo[(size_t)wave * ND + lane] = f2bf_rne(a - bf2f(ah));
    e_lo[(size_t)wave * ND + lane + 64] = f2bf_rne(b - bf2f(bh));
    float s = a * a + b * b;
#pragma unroll
    for (int off = 32; off > 0; off >>= 1) s += __shfl_down(s, off, 64);
    if (lane == 0) enorm[wave] = s;
}

// ---------------------------------------------------------------------------
// Kernel 2: MFMA argmin (R9 structure: waves_per_eu(2,2) pins 256-reg
// budget, ni-major B frags). Appends small-margin rows to rescue list and
// initializes their rpart slot to ~0 for the rescue atomicMin.
// ---------------------------------------------------------------------------
#define ZST 136   // LDS row stride in ushort

__global__ void
__attribute__((amdgpu_flat_work_group_size(256, 256), amdgpu_waves_per_eu(2, 2)))
mfma_argmin_kernel(const float* __restrict__ z,
                   const unsigned short* __restrict__ e_hi,
                   const unsigned short* __restrict__ e_lo,
                   const float* __restrict__ enorm,
                   int* __restrict__ idx_out,
                   int* __restrict__ rcount,
                   int* __restrict__ rlist,
                   unsigned long long* __restrict__ rpart) {
    __shared__ unsigned short zh[64 * ZST];
    __shared__ unsigned short zl[64 * ZST];
    __shared__ float redb1[NSLICE * 64];
    __shared__ float redb2[NSLICE * 64];
    __shared__ int redi1[NSLICE * 64];

    const int bid = blockIdx.x;
    const int rowbase = bid * 64;
    const int t = threadIdx.x;

    const float4* zg = (const float4*)(z + (size_t)rowbase * ND);
#pragma unroll
    for (int q = 0; q < 8; q++) {
        int i = t + 256 * q;               // 0..2047
        float4 v = zg[i];
        int r = i >> 5;
        int c4 = (i & 31) << 2;
        unsigned short h0 = f2bf_rne(v.x), h1 = f2bf_rne(v.y),
                       h2 = f2bf_rne(v.z), h3 = f2bf_rne(v.w);
        ushort4 hv = make_ushort4(h0, h1, h2, h3);
        ushort4 lv = make_ushort4(f2bf_rne(v.x - bf2f(h0)),
                                  f2bf_rne(v.y - bf2f(h1)),
                                  f2bf_rne(v.z - bf2f(h2)),
                                  f2bf_rne(v.w - bf2f(h3)));
        *(ushort4*)&zh[r * ZST + c4] = hv;
        *(ushort4*)&zl[r * ZST + c4] = lv;
    }
    __syncthreads();

    const int lane = t & 63;
    const int wid = __builtin_amdgcn_readfirstlane(t >> 6);
    const int quad = lane >> 4;
    const int c = lane & 15;
    const int n0 = wid * SLICE_K;

    float b1[4][4], b2[4][4];
    int i1[4][4];
#pragma unroll
    for (int mi = 0; mi < 4; mi++)
#pragma unroll
        for (int r = 0; r < 4; r++) { b1[mi][r] = 3.4e38f; b2[mi][r] = 3.4e38f; i1[mi][r] = 0; }

    const int aoff = c * ZST + quad * 8;
    const unsigned short* pbh = e_hi + c * ND + quad * 8;
    const unsigned short* pbl = e_lo + c * ND + quad * 8;

    for (int nb = n0; nb < n0 + SLICE_K; nb += 64) {
        f32x4 acc[4][4];
#pragma unroll
        for (int mi = 0; mi < 4; mi++)
#pragma unroll
            for (int ni = 0; ni < 4; ni++) acc[mi][ni] = (f32x4){0.f, 0.f, 0.f, 0.f};

#pragma unroll
        for (int kk = 0; kk < 4; kk++) {
            bf16x8 ah[4], al[4];
#pragma unroll
            for (int mi = 0; mi < 4; mi++) {
                ah[mi] = *(const bf16x8*)&zh[aoff + mi * (16 * ZST) + kk * 32];
                al[mi] = *(const bf16x8*)&zl[aoff + mi * (16 * ZST) + kk * 32];
            }
#pragma unroll
            for (int ni = 0; ni < 4; ni++) {
                size_t boff = (size_t)(nb + ni * 16) * ND + kk * 32;
                bf16x8 bhv = *(const bf16x8*)(pbh + boff);
                bf16x8 blv = *(const bf16x8*)(pbl + boff);
#pragma unroll
                for (int mi = 0; mi < 4; mi++) {
                    acc[mi][ni] = __builtin_amdgcn_mfma_f32_16x16x32_bf16(ah[mi], bhv, acc[mi][ni], 0, 0, 0);
                    acc[mi][ni] = __builtin_amdgcn_mfma_f32_16x16x32_bf16(ah[mi], blv, acc[mi][ni], 0, 0, 0);
                    acc[mi][ni] = __builtin_amdgcn_mfma_f32_16x16x32_bf16(al[mi], bhv, acc[mi][ni], 0, 0, 0);
                }
            }
        }

#pragma unroll
        for (int ni = 0; ni < 4; ni++) {
            int n = nb + ni * 16 + c;
            float en = enorm[n];
#pragma unroll
            for (int mi = 0; mi < 4; mi++)
#pragma unroll
                for (int r = 0; r < 4; r++) {
                    float s = fmaf(-2.0f, acc[mi][ni][r], en);
                    if (s < b1[mi][r]) { b2[mi][r] = b1[mi][r]; b1[mi][r] = s; i1[mi][r] = n; }
                    else if (s < b2[mi][r]) b2[mi][r] = s;
                }
        }
    }

#pragma unroll
    for (int off = 1; off < 16; off <<= 1) {
#pragma unroll
        for (int mi = 0; mi < 4; mi++)
#pragma unroll
            for (int r = 0; r < 4; r++) {
                float ob1 = __shfl_xor(b1[mi][r], off, 64);
                float ob2 = __shfl_xor(b2[mi][r], off, 64);
                int oi1 = __shfl_xor(i1[mi][r], off, 64);
                float lo = fminf(b1[mi][r], ob1);
                float hi = fmaxf(b1[mi][r], ob1);
                b2[mi][r] = fminf(fminf(b2[mi][r], ob2), hi);
                i1[mi][r] = (ob1 < b1[mi][r]) ? oi1 : i1[mi][r];
                b1[mi][r] = lo;
            }
    }

    if (c == 0) {
#pragma unroll
        for (int mi = 0; mi < 4; mi++)
#pragma unroll
            for (int r = 0; r < 4; r++) {
                int row = mi * 16 + quad * 4 + r;
                redb1[wid * 64 + row] = b1[mi][r];
                redb2[wid * 64 + row] = b2[mi][r];
                redi1[wid * 64 + row] = i1[mi][r];
            }
    }
    __syncthreads();

    if (t < 64) {
        float B1 = redb1[t], B2 = redb2[t];
        int I1 = redi1[t];
#pragma unroll
        for (int sl = 1; sl < NSLICE; sl++) {
            float ob1 = redb1[sl * 64 + t];
            float ob2 = redb2[sl * 64 + t];
            int oi1 = redi1[sl * 64 + t];
            float lo = fminf(B1, ob1);
            float hi = fmaxf(B1, ob1);
            B2 = fminf(fminf(B2, ob2), hi);
            I1 = (ob1 < B1) ? oi1 : I1;
            B1 = lo;
        }
        idx_out[rowbase + t] = I1;
        if (B2 - B1 < MARGIN_F) {
            rpart[rowbase + t] = ~0ull;          // init for rescue atomicMin
            int p = atomicAdd(rcount, 1);
            rlist[p] = rowbase + t;
        }
    }
}

// ---------------------------------------------------------------------------
// Kernel 3: exact fp32 rescue. R9 failed on uncoalesced per-thread emb row
// streams (554MB HBM, 0.3% VALU) + too few blocks. Now: work item =
// (4-row group) x (512-code slice), grid-stride; emb chunk of 64 codes
// staged TRANSPOSED in LDS (coalesced global reads, stride-65 float2 ->
// conflict-free compute reads); z rows staged once (wave-uniform reads).
// Thread = (row r = t>>6, code c = t&63); result merged via packed u64
// atomicMin (first-index tie-break exact).
// ---------------------------------------------------------------------------
#define RR 4        // rows per group
#define SC 512      // codes per slice
#define CH 64       // codes per staged chunk

__global__ void __launch_bounds__(256, 2)
rescue_kernel(const float* __restrict__ z,
              const float* __restrict__ emb,
              const float* __restrict__ enorm,
              const int* __restrict__ rcount,
              const int* __restrict__ rlist,
              unsigned long long* __restrict__ rpart) {
    __shared__ float2 ze[64 * RR];       // ze[d2*RR + r]
    __shared__ float2 es[64 * 65];       // es[d2*65 + code]
    __shared__ int ids[RR];

    const int t = threadIdx.x;
    const int cnt = *rcount;
    if (cnt == 0) return;
    const int ngrp = (cnt + RR - 1) / RR;
    const int nwork = ngrp * 8;

    const int r = t >> 6;                // 0..3 (== wave id)
    const int cl = t & 63;

    for (int g = blockIdx.x; g < nwork; g += gridDim.x) {
        const int gi = g >> 3;
        const int slice = g & 7;

        if (t < RR) {
            int j = gi * RR + t;
            ids[t] = rlist[j < cnt ? j : cnt - 1];
        }
        __syncthreads();                 // publish ids
        const int row = ids[r];
        ze[cl * RR + r] = ((const float2*)(z + (size_t)row * ND))[cl];  // coalesced

        unsigned long long bestp = ~0ull;
        const int kbase = slice * SC;

        for (int ch = 0; ch < SC / CH; ch++) {
            __syncthreads();             // es safe to overwrite (also publishes ze on ch==0)
#pragma unroll
            for (int q = 0; q < 16; q++) {
                int i = t + 256 * q;     // 0..4095
                int code = i >> 6;
                int d2 = i & 63;
                float2 v = ((const float2*)(emb + (size_t)(kbase + ch * CH + code) * ND))[d2];
                es[d2 * 65 + code] = v;
            }
            __syncthreads();

            int k = kbase + ch * CH + cl;
            float a0 = 0.f, a1 = 0.f, a2 = 0.f, a3 = 0.f;
#pragma unroll
            for (int d2 = 0; d2 < 64; d2 += 2) {
                float2 zv0 = ze[d2 * RR + r];            // wave-uniform
                float2 ev0 = es[d2 * 65 + cl];           // conflict-free
                float2 zv1 = ze[(d2 + 1) * RR + r];
                float2 ev1 = es[(d2 + 1) * 65 + cl];
                a0 = fmaf(zv0.x, ev0.x, a0);
                a1 = fmaf(zv0.y, ev0.y, a1);
                a2 = fmaf(zv1.x, ev1.x, a2);
                a3 = fmaf(zv1.y, ev1.y, a3);
            }
            float s = fmaf(-2.0f, (a0 + a1) + (a2 + a3), enorm[k]);
            unsigned long long p = pack_si(s, k);
            bestp = (p < bestp) ? p : bestp;
        }

        // wave-reduce min (all lanes in this wave share the same row)
#pragma unroll
        for (int off = 32; off > 0; off >>= 1) {
            unsigned long long o = __shfl_down(bestp, off, 64);
            bestp = (o < bestp) ? o : bestp;
        }
        if (cl == 0) atomicMin(&rpart[row], bestp);
        __syncthreads();                 // protect ids/ze before next g
    }
}

// ---------------------------------------------------------------------------
// Kernel 4: rescue finalize — unpack winning idx per rescue row.
// ---------------------------------------------------------------------------
__global__ void rescue_fin_kernel(const int* __restrict__ rcount,
                                  const int* __restrict__ rlist,
                                  const unsigned long long* __restrict__ rpart,
                                  int* __restrict__ idx_out) {
    const int cnt = *rcount;
    for (int i = blockIdx.x * blockDim.x + threadIdx.x; i < cnt;
         i += gridDim.x * blockDim.x) {
        int row = rlist[i];
        idx_out[row] = (int)(rpart[row] & 0xffffffffull);
    }
}

// ---------------------------------------------------------------------------
// Kernel 5: gather + loss partial + transposed write (unchanged).
// ---------------------------------------------------------------------------
__global__ void out_kernel(const float* __restrict__ z,
                           const float* __restrict__ emb,
                           const int* __restrict__ idx,
                           float* __restrict__ out,
                           float* __restrict__ losspart) {
    __shared__ float zq[64 * 129];
    __shared__ int ids[64];
    __shared__ float redl[4];

    const int bid = blockIdx.x;
    const int b = bid >> 6;
    const int h = bid & 63;
    const int rowbase = bid * 64;
    const int t = threadIdx.x;

    if (t < 64) ids[t] = idx[rowbase + t];
    __syncthreads();

    const int d = t & 127;
    const int w0 = t >> 7;
    float lsum = 0.f;
#pragma unroll
    for (int wq = 0; wq < 32; wq++) {
        int w = w0 + 2 * wq;
        float e = emb[(size_t)ids[w] * ND + d];
        float zv = z[((size_t)(rowbase + w)) * ND + d];
        float df = e - zv;
        lsum = fmaf(df, df, lsum);
        zq[w * 129 + d] = e;
    }
#pragma unroll
    for (int off = 32; off > 0; off >>= 1) lsum += __shfl_down(lsum, off, 64);
    if ((t & 63) == 0) redl[t >> 6] = lsum;
    __syncthreads();
    if (t == 0) losspart[bid] = redl[0] + redl[1] + redl[2] + redl[3];

    const int w = t & 63;
    const int dq = t >> 6;
#pragma unroll
    for (int dd0 = 0; dd0 < 32; dd0++) {
        int dd = dq + 4 * dd0;
        out[(((size_t)b * ND + dd) * NH + h) * NW + w] = zq[w * 129 + dd];
    }
}

// ---------------------------------------------------------------------------
// Kernel 6: final loss reduce
// ---------------------------------------------------------------------------
__global__ void loss_kernel(const float* __restrict__ losspart,
                            float* __restrict__ out) {
    __shared__ float redl[4];
    const int t = threadIdx.x;
    float s = 0.f;
#pragma unroll
    for (int i = 0; i < 4; i++) s += losspart[t + 256 * i];
#pragma unroll
    for (int off = 32; off > 0; off >>= 1) s += __shfl_down(s, off, 64);
    if ((t & 63) == 0) redl[t >> 6] = s;
    __syncthreads();
    if (t == 0) {
        float total = redl[0] + redl[1] + redl[2] + redl[3];
        out[OUT_ELEMS] = 1.25f * total / (float)OUT_ELEMS;
    }
}

// ---------------------------------------------------------------------------
extern "C" void kernel_launch(void* const* d_in, const int* in_sizes, int n_in,
                              void* d_out, int out_size, void* d_ws, size_t ws_size,
                              hipStream_t stream) {
    const float* z = (const float*)d_in[0];      // [16,64,64,128] fp32
    const float* emb = (const float*)d_in[1];    // [4096,128] fp32
    float* out = (float*)d_out;                  // 8388608 + 1 fp32

    char* ws = (char*)d_ws;
    int* ws_idx = (int*)ws;                                         // 256 KB
    float* ws_enorm = (float*)(ws + (256 << 10));                   // 16 KB
    float* ws_losspart = (float*)(ws + (272 << 10));                // 4 KB
    int* ws_rcount = (int*)(ws + (276 << 10));                      // 1 KB
    int* ws_rlist = (int*)(ws + (277 << 10));                       // 256 KB
    unsigned short* ws_ehi = (unsigned short*)(ws + (533 << 10));   // 1 MB
    unsigned short* ws_elo = (unsigned short*)(ws + (1557 << 10));  // 1 MB
    unsigned long long* ws_rpart = (unsigned long long*)(ws + (2581 << 10)); // 512 KB

    hipMemsetAsync(ws_rcount, 0, sizeof(int), stream);
    emb_prep_kernel<<<NK / 4, 256, 0, stream>>>(emb, ws_enorm, ws_ehi, ws_elo);
    mfma_argmin_kernel<<<NROWS / 64, 256, 0, stream>>>(z, ws_ehi, ws_elo,
                                                       ws_enorm, ws_idx,
                                                       ws_rcount, ws_rlist,
                                                       ws_rpart);
    rescue_kernel<<<2048, 256, 0, stream>>>(z, emb, ws_enorm, ws_rcount,
                                            ws_rlist, ws_rpart);
    rescue_fin_kernel<<<64, 256, 0, stream>>>(ws_rcount, ws_rlist, ws_rpart,
                                              ws_idx);
    out_kernel<<<NB * NH, 256, 0, stream>>>(z, emb, ws_idx, out, ws_losspart);
    loss_kernel<<<1, 256, 0, stream>>>(ws_losspart, out);
}